// Round 8
// baseline (1434.038 us; speedup 1.0000x reference)
//
#include <hip/hip_runtime.h>

#define SEQ 2048
#define BATCH 512
#define HDIM 128

typedef float f32x2 __attribute__((ext_vector_type(2)));

__device__ __forceinline__ float fast_tanh(float x) {
    // tanh(x) = 1 - 2/(exp(2x)+1); exact saturation at +/-inf.
    float e = __expf(2.0f * x);
    return fmaf(-2.0f, __builtin_amdgcn_rcpf(e + 1.0f), 1.0f);
}

// x + dpp_mov<CTRL>(x); old=0 so unselected/invalid lanes contribute 0.
template<int CTRL>
__device__ __forceinline__ float dpp_add(float x) {
    return x + __int_as_float(__builtin_amdgcn_update_dpp(
        0, __float_as_int(x), CTRL, 0xf, 0xf, false));
}

__global__ __launch_bounds__(256, 1)
void odenet_scan_kernel(const float* __restrict__ x,
                        const float* __restrict__ W1,
                        const float* __restrict__ b1,
                        const float* __restrict__ W2,
                        const float* __restrict__ b2,
                        const float* __restrict__ W3,
                        const float* __restrict__ b3,
                        float* __restrict__ out)
{
    const int t  = threadIdx.x;
    const int l  = t & 63;            // lane
    const int w  = t >> 6;            // wave 0..3: owns output cols [32w, 32w+32)
    const int pr = l >> 2;            // pair index: cols 32w+2pr, 32w+2pr+1
    const int kq = l & 3;             // K-quarter: k in [32kq, 32kq+32)
    const int c0 = 32 * w + 2 * pr;   // first of this lane's 2 output columns
    const int b0 = 2 * blockIdx.x;    // TWO chains per block: b0, b0+1

    __shared__ float2 xbuf[SEQ];            // 16 KB: x pairs (chainA, chainB)
    __shared__ float  h1buf[4][2][4 * 36];  // [wave][chain][padded h1]
    __shared__ float2 ybuf[2][4];           // [parity][wave] = {partialA, partialB}

    // ---- one-time: preload x for both chains (b0, b0+1 adjacent in memory).
    {
        float2 v[8];
        #pragma unroll
        for (int i = 0; i < 8; ++i)
            v[i] = *reinterpret_cast<const float2*>(&x[(i * 256 + t) * BATCH + b0]);
        #pragma unroll
        for (int i = 0; i < 8; ++i)
            xbuf[i * 256 + t] = v[i];
    }

    // ---- one-time: pin W2 sub-block: 2 cols x 32 k, K-packed into f32x2.
    //      Shared by both chains.
    f32x2 wA[16], wB[16];
    #pragma unroll
    for (int i = 0; i < 16; ++i) {
        const int k0 = 32 * kq + 2 * i;
        wA[i] = f32x2{W2[k0 * HDIM + c0],     W2[(k0 + 1) * HDIM + c0]};
        wB[i] = f32x2{W2[k0 * HDIM + c0 + 1], W2[(k0 + 1) * HDIM + c0 + 1]};
    }

    // h1 params for the two h-columns (2l, 2l+1) this lane produces (per wave).
    const float2 w1x = *reinterpret_cast<const float2*>(&W1[2 * l]);
    const float2 w1s = *reinterpret_cast<const float2*>(&W1[HDIM + 2 * l]);
    const float2 b1v = *reinterpret_cast<const float2*>(&b1[2 * l]);
    // layer-2/3 params; w3 pre-scaled by 0.25 (each col duplicated x4 in quad).
    const float2 b2v = *reinterpret_cast<const float2*>(&b2[c0]);
    const float w3s0 = W3[(c0 + 0) * 2 + 1] * 0.25f;
    const float w3s1 = W3[(c0 + 1) * 2 + 1] * 0.25f;
    const float b31  = b3[1];

    // h write offset: position p=2l -> group p>>5 (=l>>4), slot p&31.
    const int hoff = 36 * (l >> 4) + ((2 * l) & 31);
    const float4* hA4 = reinterpret_cast<const float4*>(&h1buf[w][0][36 * kq]);
    const float4* hB4 = reinterpret_cast<const float4*>(&h1buf[w][1][36 * kq]);

    __syncthreads();   // preload visible to all waves

    float sA = 0.0f, sB = 0.0f;
    float s_hold = 0.0f;
    float2 xn = xbuf[0];

    for (int n = 0; n < SEQ; ++n) {
        const int par = n & 1;

        // ---- layer 1, both chains: two h columns each -> wave-private LDS.
        float haA = fast_tanh(fmaf(w1x.x, xn.x, fmaf(w1s.x, sA, b1v.x)));
        float haB = fast_tanh(fmaf(w1x.x, xn.y, fmaf(w1s.x, sB, b1v.x)));
        float hbA = fast_tanh(fmaf(w1x.y, xn.x, fmaf(w1s.y, sA, b1v.y)));
        float hbB = fast_tanh(fmaf(w1x.y, xn.y, fmaf(w1s.y, sB, b1v.y)));
        *reinterpret_cast<float2*>(&h1buf[w][0][hoff]) = make_float2(haA, hbA);
        *reinterpret_cast<float2*>(&h1buf[w][1][hoff]) = make_float2(haB, hbB);
        __builtin_amdgcn_wave_barrier();   // order in-wave LDS write -> reads

        // next step's x pair from LDS (broadcast, off critical path)
        float2 xnext = xbuf[(n + 1) & (SEQ - 1)];

        // ---- layer 2, both chains interleaved: 16 b128 reads, 64 v_pk_fma_f32.
        f32x2 aA0 = {0.0f, 0.0f}, aA1 = {0.0f, 0.0f};   // chain A, cols c0,c0+1
        f32x2 aB0 = {0.0f, 0.0f}, aB1 = {0.0f, 0.0f};   // chain B
        #pragma unroll
        for (int i = 0; i < 8; ++i) {
            float4 hva = hA4[i];
            float4 hvb = hB4[i];
            f32x2 a0 = {hva.x, hva.y}, a1 = {hva.z, hva.w};
            f32x2 bq0 = {hvb.x, hvb.y}, bq1 = {hvb.z, hvb.w};
            aA0 = __builtin_elementwise_fma(wA[2 * i],     a0,  aA0);
            aB0 = __builtin_elementwise_fma(wA[2 * i],     bq0, aB0);
            aA1 = __builtin_elementwise_fma(wB[2 * i],     a0,  aA1);
            aB1 = __builtin_elementwise_fma(wB[2 * i],     bq0, aB1);
            aA0 = __builtin_elementwise_fma(wA[2 * i + 1], a1,  aA0);
            aB0 = __builtin_elementwise_fma(wA[2 * i + 1], bq1, aB0);
            aA1 = __builtin_elementwise_fma(wB[2 * i + 1], a1,  aA1);
            aB1 = __builtin_elementwise_fma(wB[2 * i + 1], bq1, aB1);
        }
        __builtin_amdgcn_wave_barrier();   // keep reads before next iter's write

        // ---- horizontal + K-quarter combine within quad (2 DPP adds per col).
        float pA0 = aA0.x + aA0.y, pA1 = aA1.x + aA1.y;
        float pB0 = aB0.x + aB0.y, pB1 = aB1.x + aB1.y;
        pA0 = dpp_add<0xB1>(pA0); pB0 = dpp_add<0xB1>(pB0);
        pA1 = dpp_add<0xB1>(pA1); pB1 = dpp_add<0xB1>(pB1);
        pA0 = dpp_add<0x4E>(pA0); pB0 = dpp_add<0x4E>(pB0);
        pA1 = dpp_add<0x4E>(pA1); pB1 = dpp_add<0x4E>(pB1);

        // ---- layer 2 tanh + W3 col-1 dot (cols duplicated x4; w3 prescaled).
        float zA = fast_tanh(pA0 + b2v.x) * w3s0;
        float zB = fast_tanh(pB0 + b2v.x) * w3s0;
        zA = fmaf(fast_tanh(pA1 + b2v.y), w3s1, zA);
        zB = fmaf(fast_tanh(pB1 + b2v.y), w3s1, zB);

        // ---- wave64 sum: row_shr/bcast cascade; full sum lands in lane 63.
        zA = dpp_add<0x111>(zA); zB = dpp_add<0x111>(zB);
        zA = dpp_add<0x112>(zA); zB = dpp_add<0x112>(zB);
        zA = dpp_add<0x114>(zA); zB = dpp_add<0x114>(zB);
        zA = dpp_add<0x118>(zA); zB = dpp_add<0x118>(zB);
        zA = dpp_add<0x142>(zA); zB = dpp_add<0x142>(zB);
        zA = dpp_add<0x143>(zA); zB = dpp_add<0x143>(zB);

        if (l == 63) ybuf[par][w] = make_float2(zA, zB);
        __syncthreads();   // ONE barrier serves BOTH chains' steps

        const float4 y01 = *reinterpret_cast<const float4*>(&ybuf[par][0]);
        const float4 y23 = *reinterpret_cast<const float4*>(&ybuf[par][2]);
        sA = sA + ((y01.x + y01.z) + (y23.x + y23.z)) + b31;
        sB = sB + ((y01.y + y01.w) + (y23.y + y23.w)) + b31;

        // ---- out batching: wave0 stores chain A, wave1 stores chain B.
        if (w == 0) {
            if (l == (n & 63)) s_hold = sA;
            if ((n & 63) == 63) out[(n - 63 + l) * BATCH + b0] = s_hold;
        } else if (w == 1) {
            if (l == (n & 63)) s_hold = sB;
            if ((n & 63) == 63) out[(n - 63 + l) * BATCH + b0 + 1] = s_hold;
        }
        xn = xnext;
    }
}

extern "C" void kernel_launch(void* const* d_in, const int* in_sizes, int n_in,
                              void* d_out, int out_size, void* d_ws, size_t ws_size,
                              hipStream_t stream) {
    const float* x  = (const float*)d_in[0];
    const float* W1 = (const float*)d_in[1];
    const float* b1 = (const float*)d_in[2];
    const float* W2 = (const float*)d_in[3];
    const float* b2 = (const float*)d_in[4];
    const float* W3 = (const float*)d_in[5];
    const float* b3 = (const float*)d_in[6];
    float* out = (float*)d_out;

    dim3 grid(BATCH / 2);   // two chains per block
    dim3 block(256);        // 4 waves
    odenet_scan_kernel<<<grid, block, 0, stream>>>(x, W1, b1, W2, b2, W3, b3, out);
}